// Round 2
// baseline (355.225 us; speedup 1.0000x reference)
//
#include <hip/hip_runtime.h>

// B=4096 batches, D=100 features, T=100 timesteps, O=3 outputs.
#define NB 4096
#define ND 100
#define NT 100
#define NO 3

// Fully fused: one block per batch b.
// Phase 1: 10 half-waves (32 lanes each); half-wave hw handles rows t = hw+10*iter.
//   Lanes 0..24 of each half load one float4 of x,u (row is 25 float4s, 16B-aligned
//   since rows are 400 B), form spikes, FMA against register-resident W fragments,
//   then 5-step __shfl_xor reduce (masks 1..16 stay within the 32-lane half).
//   Lane 0 writes cur[t][0..2] to LDS.
// Phase 2: threads 0..2 run the sequential leaky scan from LDS, writing
//   spk/mem directly to global (12 B per t per block; sector amplification ~2.7x
//   on 20 MB of writes is cheaper than a second latency-bound kernel).
__global__ __launch_bounds__(320) void fused_leaky(
    const float* __restrict__ x, const float* __restrict__ u,
    const float* __restrict__ W, const float* __restrict__ bias,
    const float* __restrict__ beta_p, const float* __restrict__ thr_p,
    float* __restrict__ out)
{
    __shared__ float cur_s[NT * 4];   // stride 4: scan reads t*4+o, no conflicts

    const int b   = blockIdx.x;
    const int tid = threadIdx.x;
    const int hw  = tid >> 5;         // 0..9  half-wave id == row group
    const int l   = tid & 31;         // lane within half-wave

    // Register-resident weight fragments: W[o][4l .. 4l+3] (W rows are 400 B -> 16B aligned)
    float4 w0 = {0,0,0,0}, w1 = {0,0,0,0}, w2 = {0,0,0,0};
    if (l < 25) {
        w0 = ((const float4*)(W         ))[l];
        w1 = ((const float4*)(W +    ND))[l];
        w2 = ((const float4*)(W + 2*ND ))[l];
    }

    const float* xb = x + (size_t)b * (ND * ND);
    const float* ub = u + (size_t)b * (ND * ND);

    for (int iter = 0; iter < 10; ++iter) {
        const int t = hw + 10 * iter;
        float a0 = 0.f, a1 = 0.f, a2 = 0.f;
        if (l < 25) {
            const float4 xv = ((const float4*)(xb + t * ND))[l];
            const float4 uv = ((const float4*)(ub + t * ND))[l];
            const float s0 = (uv.x < xv.x) ? 1.f : 0.f;
            const float s1 = (uv.y < xv.y) ? 1.f : 0.f;
            const float s2 = (uv.z < xv.z) ? 1.f : 0.f;
            const float s3 = (uv.w < xv.w) ? 1.f : 0.f;
            a0 = fmaf(s3, w0.w, fmaf(s2, w0.z, fmaf(s1, w0.y, s0 * w0.x)));
            a1 = fmaf(s3, w1.w, fmaf(s2, w1.z, fmaf(s1, w1.y, s0 * w1.x)));
            a2 = fmaf(s3, w2.w, fmaf(s2, w2.z, fmaf(s1, w2.y, s0 * w2.x)));
        }
        // reduce across the 32-lane half (xor masks < 32 never cross halves)
        #pragma unroll
        for (int m = 1; m < 32; m <<= 1) {
            a0 += __shfl_xor(a0, m);
            a1 += __shfl_xor(a1, m);
            a2 += __shfl_xor(a2, m);
        }
        if (l == 0) {
            cur_s[t * 4 + 0] = a0;
            cur_s[t * 4 + 1] = a1;
            cur_s[t * 4 + 2] = a2;
        }
    }
    __syncthreads();

    // Sequential leaky scan: threads 0..2, o = tid.
    if (tid < NO) {
        const int   o    = tid;
        const float beta = beta_p[0];
        const float thr  = thr_p[0];
        const float bo   = bias[o];
        const int   col  = b * NO + o;
        float* mem_rec = out + (size_t)NT * NB * NO;

        float mem = 0.f;
        #pragma unroll 4
        for (int t = 0; t < NT; ++t) {
            const float cv   = cur_s[t * 4 + o] + bo;           // fc1 + bias
            const float rsub = (mem > thr) ? thr : 0.f;         // reset from PREV mem
            // match numpy elementwise order: (beta*mem + cur) - reset*thr, no FMA fusion
            mem = __fadd_rn(__fadd_rn(__fmul_rn(beta, mem), cv), -rsub);
            const float s = (mem > thr) ? 1.f : 0.f;
            out[(size_t)t * (NB * NO) + col]     = s;
            mem_rec[(size_t)t * (NB * NO) + col] = mem;
        }
    }
}

extern "C" void kernel_launch(void* const* d_in, const int* in_sizes, int n_in,
                              void* d_out, int out_size, void* d_ws, size_t ws_size,
                              hipStream_t stream) {
    const float* x    = (const float*)d_in[0];   // [4096,100,100]
    const float* u    = (const float*)d_in[1];   // [4096,100,100]
    const float* W    = (const float*)d_in[2];   // [3,100]
    const float* bias = (const float*)d_in[3];   // [3]
    const float* beta = (const float*)d_in[4];   // scalar
    const float* thr  = (const float*)d_in[5];   // scalar
    float* out = (float*)d_out;

    fused_leaky<<<NB, 320, 0, stream>>>(x, u, W, bias, beta, thr, out);
}